// Round 1
// baseline (1405.313 us; speedup 1.0000x reference)
//
#include <hip/hip_runtime.h>

constexpr int NN = 100000;
constexpr int NE = 1600000;

// Kernel 1: out[n][d] = x[n][d] * (1 + eps)   (base value for the segment-sum)
__global__ __launch_bounds__(256) void k_init(const float* __restrict__ x,
                                              const float* __restrict__ eps,
                                              float* __restrict__ out) {
    const float s = 1.0f + eps[0];
    const float4* x4 = (const float4*)x;
    float4* o4 = (float4*)out;
    const int total = NN * 16;  // float4 count
    for (int i = blockIdx.x * blockDim.x + threadIdx.x; i < total;
         i += gridDim.x * blockDim.x) {
        float4 v = x4[i];
        v.x *= s; v.y *= s; v.z *= s; v.w *= s;
        o4[i] = v;
    }
}

// Kernel 2: out[dst] += relu(x[src] + edge_attr)  via fp32 atomics.
// Element mapping: g = e*16 + c, c indexes the float4 within the 64-float row
// -> edge_attr reads fully coalesced; 16 consecutive lanes share one edge.
__global__ __launch_bounds__(256) void k_edges(const float* __restrict__ x,
                                               const int* __restrict__ ei,
                                               const float* __restrict__ ea,
                                               float* __restrict__ out) {
    const int* dst = ei;         // edge_index[0]
    const int* src = ei + NE;    // edge_index[1]
    const float4* ea4 = (const float4*)ea;
    const float4* x4 = (const float4*)x;
    const int total = NE * 16;   // float4 count
    for (int g = blockIdx.x * blockDim.x + threadIdx.x; g < total;
         g += gridDim.x * blockDim.x) {
        const int e = g >> 4;
        const int c = g & 15;
        const int s = src[e];
        const int d = dst[e];
        float4 a  = ea4[g];
        float4 xv = x4[s * 16 + c];
        const float mx = fmaxf(xv.x + a.x, 0.0f);
        const float my = fmaxf(xv.y + a.y, 0.0f);
        const float mz = fmaxf(xv.z + a.z, 0.0f);
        const float mw = fmaxf(xv.w + a.w, 0.0f);
        float* base = out + d * 64 + c * 4;
        atomicAdd(base + 0, mx);
        atomicAdd(base + 1, my);
        atomicAdd(base + 2, mz);
        atomicAdd(base + 3, mw);
    }
}

// Kernel 3: in-place per-row linear: out[n] = h[n] @ W + b, h = current out row.
// W staged in LDS (uniform-index broadcast reads, conflict-free).
// One thread per node; row held in registers (all indices static after unroll).
__global__ __launch_bounds__(256) void k_linear(const float* __restrict__ W,
                                                const float* __restrict__ bias,
                                                float* __restrict__ out) {
    __shared__ float Ws[64 * 64];
    __shared__ float bs[64];
    for (int i = threadIdx.x; i < 1024; i += blockDim.x)
        ((float4*)Ws)[i] = ((const float4*)W)[i];
    if (threadIdx.x < 16)
        ((float4*)bs)[threadIdx.x] = ((const float4*)bias)[threadIdx.x];
    __syncthreads();

    const int n = blockIdx.x * blockDim.x + threadIdx.x;
    if (n >= NN) return;

    float4* row = (float4*)(out + n * 64);
    float h[64];
#pragma unroll
    for (int k = 0; k < 16; ++k) {
        float4 v = row[k];
        h[4 * k + 0] = v.x; h[4 * k + 1] = v.y;
        h[4 * k + 2] = v.z; h[4 * k + 3] = v.w;
    }
#pragma unroll
    for (int jt = 0; jt < 4; ++jt) {          // 4 tiles of 16 outputs
        float acc[16];
#pragma unroll
        for (int j = 0; j < 16; ++j) acc[j] = bs[jt * 16 + j];
#pragma unroll
        for (int d = 0; d < 64; ++d) {
            const float hd = h[d];
#pragma unroll
            for (int j = 0; j < 16; ++j)
                acc[j] = fmaf(hd, Ws[d * 64 + jt * 16 + j], acc[j]);
        }
#pragma unroll
        for (int j = 0; j < 4; ++j)
            row[jt * 4 + j] = make_float4(acc[4 * j + 0], acc[4 * j + 1],
                                          acc[4 * j + 2], acc[4 * j + 3]);
    }
}

extern "C" void kernel_launch(void* const* d_in, const int* in_sizes, int n_in,
                              void* d_out, int out_size, void* d_ws, size_t ws_size,
                              hipStream_t stream) {
    const float* x   = (const float*)d_in[0];
    const int*   ei  = (const int*)d_in[1];
    const float* ea  = (const float*)d_in[2];
    const float* eps = (const float*)d_in[3];
    const float* W   = (const float*)d_in[4];
    const float* b   = (const float*)d_in[5];
    float* out = (float*)d_out;

    k_init<<<2048, 256, 0, stream>>>(x, eps, out);
    k_edges<<<2048, 256, 0, stream>>>(x, ei, ea, out);
    k_linear<<<(NN + 255) / 256, 256, 0, stream>>>(W, b, out);
}

// Round 2
// 427.748 us; speedup vs baseline: 3.2854x; 3.2854x over previous
//
#include <hip/hip_runtime.h>

constexpr int NN = 100000;
constexpr int NE = 1600000;
constexpr int SCAN_BLK = 1024;                        // elements per scan block
constexpr int NB = (NN + SCAN_BLK - 1) / SCAN_BLK;    // 98 scan blocks

// ---------------- fallback path (round-1 kernels, used only if ws too small) --

__global__ __launch_bounds__(256) void k_init(const float* __restrict__ x,
                                              const float* __restrict__ eps,
                                              float* __restrict__ out) {
    const float s = 1.0f + eps[0];
    const float4* x4 = (const float4*)x;
    float4* o4 = (float4*)out;
    const int total = NN * 16;
    for (int i = blockIdx.x * blockDim.x + threadIdx.x; i < total;
         i += gridDim.x * blockDim.x) {
        float4 v = x4[i];
        v.x *= s; v.y *= s; v.z *= s; v.w *= s;
        o4[i] = v;
    }
}

__global__ __launch_bounds__(256) void k_edges(const float* __restrict__ x,
                                               const int* __restrict__ ei,
                                               const float* __restrict__ ea,
                                               float* __restrict__ out) {
    const int* dst = ei;
    const int* src = ei + NE;
    const float4* ea4 = (const float4*)ea;
    const float4* x4 = (const float4*)x;
    const int total = NE * 16;
    for (int g = blockIdx.x * blockDim.x + threadIdx.x; g < total;
         g += gridDim.x * blockDim.x) {
        const int e = g >> 4;
        const int c = g & 15;
        const int s = src[e];
        const int d = dst[e];
        float4 a  = ea4[g];
        float4 xv = x4[s * 16 + c];
        float* base = out + d * 64 + c * 4;
        atomicAdd(base + 0, fmaxf(xv.x + a.x, 0.0f));
        atomicAdd(base + 1, fmaxf(xv.y + a.y, 0.0f));
        atomicAdd(base + 2, fmaxf(xv.z + a.z, 0.0f));
        atomicAdd(base + 3, fmaxf(xv.w + a.w, 0.0f));
    }
}

// ---------------- sorted path --------------------------------------------------

__global__ __launch_bounds__(256) void k_zero(int* __restrict__ counts) {
    for (int i = blockIdx.x * blockDim.x + threadIdx.x; i < NN;
         i += gridDim.x * blockDim.x)
        counts[i] = 0;
}

__global__ __launch_bounds__(256) void k_hist(const int* __restrict__ dst,
                                              int* __restrict__ counts) {
    for (int e = blockIdx.x * blockDim.x + threadIdx.x; e < NE;
         e += gridDim.x * blockDim.x)
        atomicAdd(&counts[dst[e]], 1);
}

// per-block scan of 1024 counts -> block-local exclusive offsets + block sum
__global__ __launch_bounds__(256) void k_scan_block(const int* __restrict__ counts,
                                                    int* __restrict__ offsets,
                                                    int* __restrict__ bsum) {
    __shared__ int sd[256];
    const int t = threadIdx.x;
    const int base = blockIdx.x * SCAN_BLK;
    int c[4];
    int s = 0;
#pragma unroll
    for (int k = 0; k < 4; ++k) {
        const int i = base + t * 4 + k;
        c[k] = (i < NN) ? counts[i] : 0;
        s += c[k];
    }
    sd[t] = s;
    __syncthreads();
#pragma unroll
    for (int off = 1; off < 256; off <<= 1) {
        int v = (t >= off) ? sd[t - off] : 0;
        __syncthreads();
        sd[t] += v;
        __syncthreads();
    }
    int excl = sd[t] - s;   // exclusive base for this thread's 4 elements
#pragma unroll
    for (int k = 0; k < 4; ++k) {
        const int i = base + t * 4 + k;
        if (i < NN) offsets[i] = excl;
        excl += c[k];
    }
    if (t == 255) bsum[blockIdx.x] = sd[255];
}

// single-block exclusive scan of the NB block sums
__global__ __launch_bounds__(128) void k_scan_sums(const int* __restrict__ bsum,
                                                   int* __restrict__ bsum_ex) {
    __shared__ int sd[128];
    const int t = threadIdx.x;
    const int v = (t < NB) ? bsum[t] : 0;
    sd[t] = v;
    __syncthreads();
#pragma unroll
    for (int off = 1; off < 128; off <<= 1) {
        int u = (t >= off) ? sd[t - off] : 0;
        __syncthreads();
        sd[t] += u;
        __syncthreads();
    }
    bsum_ex[t] = sd[t] - v;
}

__global__ __launch_bounds__(256) void k_scan_add(int* __restrict__ offsets,
                                                  const int* __restrict__ bsum_ex,
                                                  int* __restrict__ cursor) {
    for (int i = blockIdx.x * blockDim.x + threadIdx.x; i < NN;
         i += gridDim.x * blockDim.x) {
        const int v = offsets[i] + bsum_ex[i >> 10];
        offsets[i] = v;
        cursor[i] = v;
    }
    if (blockIdx.x == 0 && threadIdx.x == 0) offsets[NN] = NE;
}

__global__ __launch_bounds__(256) void k_scatter(const int* __restrict__ dst,
                                                 int* __restrict__ cursor,
                                                 int* __restrict__ perm) {
    for (int e = blockIdx.x * blockDim.x + threadIdx.x; e < NE;
         e += gridDim.x * blockDim.x) {
        const int pos = atomicAdd(&cursor[dst[e]], 1);
        perm[pos] = e;
    }
}

// one 64-lane wave per node, lane = feature dim; fused x*(1+eps) init.
__global__ __launch_bounds__(256) void k_agg(const float* __restrict__ x,
                                             const int* __restrict__ src,
                                             const float* __restrict__ ea,
                                             const int* __restrict__ offsets,
                                             const int* __restrict__ perm,
                                             const float* __restrict__ epsp,
                                             float* __restrict__ out) {
    const int wave = threadIdx.x >> 6;
    const int lane = threadIdx.x & 63;
    const int n = blockIdx.x * 4 + wave;
    if (n >= NN) return;

    float acc = x[n * 64 + lane] * (1.0f + epsp[0]);
    const int beg = offsets[n];
    const int end = offsets[n + 1];
    int j = beg;
    for (; j + 2 <= end; j += 2) {           // 2-way unroll for MLP
        const int e0 = perm[j];
        const int e1 = perm[j + 1];
        const int s0 = src[e0];
        const int s1 = src[e1];
        const float a0 = ea[e0 * 64 + lane];
        const float a1 = ea[e1 * 64 + lane];
        const float x0 = x[s0 * 64 + lane];
        const float x1 = x[s1 * 64 + lane];
        acc += fmaxf(x0 + a0, 0.0f) + fmaxf(x1 + a1, 0.0f);
    }
    if (j < end) {
        const int e0 = perm[j];
        acc += fmaxf(x[src[e0] * 64 + lane] + ea[e0 * 64 + lane], 0.0f);
    }
    out[n * 64 + lane] = acc;
}

// in-place per-row linear: out[n] = h[n] @ W + b
__global__ __launch_bounds__(256) void k_linear(const float* __restrict__ W,
                                                const float* __restrict__ bias,
                                                float* __restrict__ out) {
    __shared__ float Ws[64 * 64];
    __shared__ float bs[64];
    for (int i = threadIdx.x; i < 1024; i += blockDim.x)
        ((float4*)Ws)[i] = ((const float4*)W)[i];
    if (threadIdx.x < 16)
        ((float4*)bs)[threadIdx.x] = ((const float4*)bias)[threadIdx.x];
    __syncthreads();

    const int n = blockIdx.x * blockDim.x + threadIdx.x;
    if (n >= NN) return;

    float4* row = (float4*)(out + n * 64);
    float h[64];
#pragma unroll
    for (int k = 0; k < 16; ++k) {
        float4 v = row[k];
        h[4 * k + 0] = v.x; h[4 * k + 1] = v.y;
        h[4 * k + 2] = v.z; h[4 * k + 3] = v.w;
    }
#pragma unroll
    for (int jt = 0; jt < 4; ++jt) {
        float acc[16];
#pragma unroll
        for (int j = 0; j < 16; ++j) acc[j] = bs[jt * 16 + j];
#pragma unroll
        for (int d = 0; d < 64; ++d) {
            const float hd = h[d];
#pragma unroll
            for (int j = 0; j < 16; ++j)
                acc[j] = fmaf(hd, Ws[d * 64 + jt * 16 + j], acc[j]);
        }
#pragma unroll
        for (int j = 0; j < 4; ++j)
            row[jt * 4 + j] = make_float4(acc[4 * j + 0], acc[4 * j + 1],
                                          acc[4 * j + 2], acc[4 * j + 3]);
    }
}

extern "C" void kernel_launch(void* const* d_in, const int* in_sizes, int n_in,
                              void* d_out, int out_size, void* d_ws, size_t ws_size,
                              hipStream_t stream) {
    const float* x   = (const float*)d_in[0];
    const int*   ei  = (const int*)d_in[1];
    const float* ea  = (const float*)d_in[2];
    const float* eps = (const float*)d_in[3];
    const float* W   = (const float*)d_in[4];
    const float* b   = (const float*)d_in[5];
    float* out = (float*)d_out;

    const int* dst = ei;        // edge_index[0]
    const int* src = ei + NE;   // edge_index[1]

    // workspace layout (ints)
    int* counts  = (int*)d_ws;            // NN
    int* offsets = counts + NN;           // NN + 1
    int* cursor  = offsets + NN + 1;      // NN
    int* bsum    = cursor + NN;           // 128
    int* bsum_ex = bsum + 128;            // 128
    int* perm    = bsum_ex + 128;         // NE
    const size_t ws_needed = (size_t)(NN * 3 + 1 + 256 + NE) * sizeof(int);

    if (ws_size < ws_needed) {            // insurance: round-1 atomic path
        k_init<<<2048, 256, 0, stream>>>(x, eps, out);
        k_edges<<<2048, 256, 0, stream>>>(x, ei, ea, out);
        k_linear<<<(NN + 255) / 256, 256, 0, stream>>>(W, b, out);
        return;
    }

    k_zero<<<128, 256, 0, stream>>>(counts);
    k_hist<<<2048, 256, 0, stream>>>(dst, counts);
    k_scan_block<<<NB, 256, 0, stream>>>(counts, offsets, bsum);
    k_scan_sums<<<1, 128, 0, stream>>>(bsum, bsum_ex);
    k_scan_add<<<256, 256, 0, stream>>>(offsets, bsum_ex, cursor);
    k_scatter<<<2048, 256, 0, stream>>>(dst, cursor, perm);
    k_agg<<<(NN + 3) / 4, 256, 0, stream>>>(x, src, ea, offsets, perm, eps, out);
    k_linear<<<(NN + 255) / 256, 256, 0, stream>>>(W, b, out);
}

// Round 3
// 388.804 us; speedup vs baseline: 3.6145x; 1.1002x over previous
//
#include <hip/hip_runtime.h>

constexpr int NN = 100000;
constexpr int NE = 1600000;
constexpr int SCAN_BLK = 1024;                        // elements per scan block
constexpr int NB = (NN + SCAN_BLK - 1) / SCAN_BLK;    // 98 scan blocks

// ---------------- fallback path (round-1 kernels, used only if ws too small) --

__global__ __launch_bounds__(256) void k_init(const float* __restrict__ x,
                                              const float* __restrict__ eps,
                                              float* __restrict__ out) {
    const float s = 1.0f + eps[0];
    const float4* x4 = (const float4*)x;
    float4* o4 = (float4*)out;
    const int total = NN * 16;
    for (int i = blockIdx.x * blockDim.x + threadIdx.x; i < total;
         i += gridDim.x * blockDim.x) {
        float4 v = x4[i];
        v.x *= s; v.y *= s; v.z *= s; v.w *= s;
        o4[i] = v;
    }
}

__global__ __launch_bounds__(256) void k_edges(const float* __restrict__ x,
                                               const int* __restrict__ ei,
                                               const float* __restrict__ ea,
                                               float* __restrict__ out) {
    const int* dst = ei;
    const int* src = ei + NE;
    const float4* ea4 = (const float4*)ea;
    const float4* x4 = (const float4*)x;
    const int total = NE * 16;
    for (int g = blockIdx.x * blockDim.x + threadIdx.x; g < total;
         g += gridDim.x * blockDim.x) {
        const int e = g >> 4;
        const int c = g & 15;
        const int s = src[e];
        const int d = dst[e];
        float4 a  = ea4[g];
        float4 xv = x4[s * 16 + c];
        float* base = out + d * 64 + c * 4;
        atomicAdd(base + 0, fmaxf(xv.x + a.x, 0.0f));
        atomicAdd(base + 1, fmaxf(xv.y + a.y, 0.0f));
        atomicAdd(base + 2, fmaxf(xv.z + a.z, 0.0f));
        atomicAdd(base + 3, fmaxf(xv.w + a.w, 0.0f));
    }
}

__global__ __launch_bounds__(256) void k_linear(const float* __restrict__ W,
                                                const float* __restrict__ bias,
                                                float* __restrict__ out) {
    __shared__ float Ws[64 * 64];
    __shared__ float bs[64];
    for (int i = threadIdx.x; i < 1024; i += blockDim.x)
        ((float4*)Ws)[i] = ((const float4*)W)[i];
    if (threadIdx.x < 16)
        ((float4*)bs)[threadIdx.x] = ((const float4*)bias)[threadIdx.x];
    __syncthreads();
    const int n = blockIdx.x * blockDim.x + threadIdx.x;
    if (n >= NN) return;
    float4* row = (float4*)(out + n * 64);
    float h[64];
#pragma unroll
    for (int k = 0; k < 16; ++k) {
        float4 v = row[k];
        h[4 * k + 0] = v.x; h[4 * k + 1] = v.y;
        h[4 * k + 2] = v.z; h[4 * k + 3] = v.w;
    }
#pragma unroll
    for (int jt = 0; jt < 4; ++jt) {
        float acc[16];
#pragma unroll
        for (int j = 0; j < 16; ++j) acc[j] = bs[jt * 16 + j];
#pragma unroll
        for (int d = 0; d < 64; ++d) {
            const float hd = h[d];
#pragma unroll
            for (int j = 0; j < 16; ++j)
                acc[j] = fmaf(hd, Ws[d * 64 + jt * 16 + j], acc[j]);
        }
#pragma unroll
        for (int j = 0; j < 4; ++j)
            row[jt * 4 + j] = make_float4(acc[4 * j + 0], acc[4 * j + 1],
                                          acc[4 * j + 2], acc[4 * j + 3]);
    }
}

// ---------------- sorted path --------------------------------------------------

__global__ __launch_bounds__(256) void k_zero(int* __restrict__ counts) {
    for (int i = blockIdx.x * blockDim.x + threadIdx.x; i < NN;
         i += gridDim.x * blockDim.x)
        counts[i] = 0;
}

__global__ __launch_bounds__(256) void k_hist(const int* __restrict__ dst,
                                              int* __restrict__ counts) {
    for (int e = blockIdx.x * blockDim.x + threadIdx.x; e < NE;
         e += gridDim.x * blockDim.x)
        atomicAdd(&counts[dst[e]], 1);
}

__global__ __launch_bounds__(256) void k_scan_block(const int* __restrict__ counts,
                                                    int* __restrict__ offsets,
                                                    int* __restrict__ bsum) {
    __shared__ int sd[256];
    const int t = threadIdx.x;
    const int base = blockIdx.x * SCAN_BLK;
    int c[4];
    int s = 0;
#pragma unroll
    for (int k = 0; k < 4; ++k) {
        const int i = base + t * 4 + k;
        c[k] = (i < NN) ? counts[i] : 0;
        s += c[k];
    }
    sd[t] = s;
    __syncthreads();
#pragma unroll
    for (int off = 1; off < 256; off <<= 1) {
        int v = (t >= off) ? sd[t - off] : 0;
        __syncthreads();
        sd[t] += v;
        __syncthreads();
    }
    int excl = sd[t] - s;
#pragma unroll
    for (int k = 0; k < 4; ++k) {
        const int i = base + t * 4 + k;
        if (i < NN) offsets[i] = excl;
        excl += c[k];
    }
    if (t == 255) bsum[blockIdx.x] = sd[255];
}

__global__ __launch_bounds__(128) void k_scan_sums(const int* __restrict__ bsum,
                                                   int* __restrict__ bsum_ex) {
    __shared__ int sd[128];
    const int t = threadIdx.x;
    const int v = (t < NB) ? bsum[t] : 0;
    sd[t] = v;
    __syncthreads();
#pragma unroll
    for (int off = 1; off < 128; off <<= 1) {
        int u = (t >= off) ? sd[t - off] : 0;
        __syncthreads();
        sd[t] += u;
        __syncthreads();
    }
    bsum_ex[t] = sd[t] - v;
}

__global__ __launch_bounds__(256) void k_scan_add(int* __restrict__ offsets,
                                                  const int* __restrict__ bsum_ex,
                                                  int* __restrict__ cursor) {
    for (int i = blockIdx.x * blockDim.x + threadIdx.x; i < NN;
         i += gridDim.x * blockDim.x) {
        const int v = offsets[i] + bsum_ex[i >> 10];
        offsets[i] = v;
        cursor[i] = v;
    }
    if (blockIdx.x == 0 && threadIdx.x == 0) offsets[NN] = NE;
}

// scatter {edge_id, src_id} pairs into dst-sorted order (one 8B store per edge)
__global__ __launch_bounds__(256) void k_scatter(const int* __restrict__ dst,
                                                 const int* __restrict__ src,
                                                 int* __restrict__ cursor,
                                                 int2* __restrict__ ps) {
    for (int e = blockIdx.x * blockDim.x + threadIdx.x; e < NE;
         e += gridDim.x * blockDim.x) {
        const int pos = atomicAdd(&cursor[dst[e]], 1);
        ps[pos] = make_int2(e, src[e]);
    }
}

// Fused aggregate + self-term + linear.
// Wave layout: 4 groups x 16 lanes; group g processes edge (jb + g); each
// 16-lane group covers a full 64-float row as float4/lane. 8 edges in flight
// (2-batch unroll). Butterfly xor-reduce folds the 4 group partials, then
// each lane computes one output dim of h @ W + b (W staged in LDS, h
// broadcast via static __shfl).
__global__ __launch_bounds__(256) void k_agg_lin(const float* __restrict__ x,
                                                 const float* __restrict__ ea,
                                                 const int* __restrict__ offsets,
                                                 const int2* __restrict__ ps,
                                                 const float* __restrict__ epsp,
                                                 const float* __restrict__ W,
                                                 const float* __restrict__ bias,
                                                 float* __restrict__ out) {
    __shared__ float Ws[64 * 64];
    __shared__ float bs[64];
    for (int i = threadIdx.x; i < 1024; i += 256)
        ((float4*)Ws)[i] = ((const float4*)W)[i];
    if (threadIdx.x < 16)
        ((float4*)bs)[threadIdx.x] = ((const float4*)bias)[threadIdx.x];
    __syncthreads();

    const float epsv = 1.0f + epsp[0];
    const int wave = threadIdx.x >> 6;
    const int lane = threadIdx.x & 63;
    const int grp = lane >> 4;
    const int l16 = lane & 15;
    const float4* x4 = (const float4*)x;
    const float4* ea4 = (const float4*)ea;

    for (int n = blockIdx.x * 4 + wave; n < NN; n += gridDim.x * 4) {
        const int beg = offsets[n];
        const int end = offsets[n + 1];
        float4 acc = make_float4(0.f, 0.f, 0.f, 0.f);

        for (int jb = beg; jb < end; jb += 8) {
            const int j0 = jb + grp;
            const int j1 = jb + 4 + grp;
            const bool a0 = j0 < end;
            const bool a1 = j1 < end;
            const int2 es0 = a0 ? ps[j0] : make_int2(0, 0);
            const int2 es1 = a1 ? ps[j1] : make_int2(0, 0);
            const float4 A0 = ea4[es0.x * 16 + l16];
            const float4 X0 = x4[es0.y * 16 + l16];
            const float4 A1 = ea4[es1.x * 16 + l16];
            const float4 X1 = x4[es1.y * 16 + l16];
            if (a0) {
                acc.x += fmaxf(X0.x + A0.x, 0.f);
                acc.y += fmaxf(X0.y + A0.y, 0.f);
                acc.z += fmaxf(X0.z + A0.z, 0.f);
                acc.w += fmaxf(X0.w + A0.w, 0.f);
            }
            if (a1) {
                acc.x += fmaxf(X1.x + A1.x, 0.f);
                acc.y += fmaxf(X1.y + A1.y, 0.f);
                acc.z += fmaxf(X1.z + A1.z, 0.f);
                acc.w += fmaxf(X1.w + A1.w, 0.f);
            }
        }

        // fold the 4 group partials: every lane ends with full sums for its
        // dims [l16*4 .. l16*4+3]
#pragma unroll
        for (int m = 16; m < 64; m <<= 1) {
            acc.x += __shfl_xor(acc.x, m);
            acc.y += __shfl_xor(acc.y, m);
            acc.z += __shfl_xor(acc.z, m);
            acc.w += __shfl_xor(acc.w, m);
        }

        // self term
        const float4 xs = x4[n * 16 + l16];
        acc.x = fmaf(xs.x, epsv, acc.x);
        acc.y = fmaf(xs.y, epsv, acc.y);
        acc.z = fmaf(xs.z, epsv, acc.z);
        acc.w = fmaf(xs.w, epsv, acc.w);

        // linear: out[n][lane] = b[lane] + sum_d h[d] * W[d][lane]
        float o = bs[lane];
#pragma unroll
        for (int d = 0; d < 64; ++d) {
            const int q = d >> 2;
            const int r = d & 3;
            float hd;
            if (r == 0)      hd = __shfl(acc.x, q);
            else if (r == 1) hd = __shfl(acc.y, q);
            else if (r == 2) hd = __shfl(acc.z, q);
            else             hd = __shfl(acc.w, q);
            o = fmaf(hd, Ws[d * 64 + lane], o);
        }
        out[n * 64 + lane] = o;
    }
}

extern "C" void kernel_launch(void* const* d_in, const int* in_sizes, int n_in,
                              void* d_out, int out_size, void* d_ws, size_t ws_size,
                              hipStream_t stream) {
    const float* x   = (const float*)d_in[0];
    const int*   ei  = (const int*)d_in[1];
    const float* ea  = (const float*)d_in[2];
    const float* eps = (const float*)d_in[3];
    const float* W   = (const float*)d_in[4];
    const float* b   = (const float*)d_in[5];
    float* out = (float*)d_out;

    const int* dst = ei;        // edge_index[0]
    const int* src = ei + NE;   // edge_index[1]

    // workspace layout (ints); pad so ps is 8B-aligned
    int* counts  = (int*)d_ws;            // NN
    int* offsets = counts + NN;           // NN + 1
    int* cursor  = offsets + NN + 1;      // NN
    int* bsum    = cursor + NN;           // 128
    int* bsum_ex = bsum + 128;            // 128
    int2* ps     = (int2*)(bsum_ex + 128 + 1);  // NE pairs (+1 pad -> 8B aligned)
    const size_t ws_needed = (size_t)(NN * 3 + 2 + 256 + 2 * NE) * sizeof(int);

    if (ws_size < ws_needed) {            // insurance: round-1 atomic path
        k_init<<<2048, 256, 0, stream>>>(x, eps, out);
        k_edges<<<2048, 256, 0, stream>>>(x, ei, ea, out);
        k_linear<<<(NN + 255) / 256, 256, 0, stream>>>(W, b, out);
        return;
    }

    k_zero<<<128, 256, 0, stream>>>(counts);
    k_hist<<<2048, 256, 0, stream>>>(dst, counts);
    k_scan_block<<<NB, 256, 0, stream>>>(counts, offsets, bsum);
    k_scan_sums<<<1, 128, 0, stream>>>(bsum, bsum_ex);
    k_scan_add<<<256, 256, 0, stream>>>(offsets, bsum_ex, cursor);
    k_scatter<<<2048, 256, 0, stream>>>(dst, src, cursor, ps);
    k_agg_lin<<<4096, 256, 0, stream>>>(x, ea, offsets, ps, eps, W, b, out);
}